// Round 10
// baseline (355.220 us; speedup 1.0000x reference)
//
#include <hip/hip_runtime.h>
#include <hip/hip_fp16.h>
#include <math.h>

// SSIM loss, fused single kernel, R7.
// Lessons: R5 - scalar global loads in inner loop = latency death.
//          R6 - VALUBusy*dur == R1's (63us): stalls, not conflicts, dominate;
//               3-phase barrier structure + staging pass adds a full
//               pack/unpack instruction pass and an extra barrier.
// R7: NO input staging. Horizontal pass loads its 24-col window as 6x float4
// per image straight into registers (12 b128 loads issued up-front, single
// vmcnt wait, then pure-register FMAs). LDS only for h-results:
// hq (half2 pairs, b128 writes / b64 reads) + hx5 fp32 = 33.6KB -> 4 blk/CU.
// ONE barrier total. Border tiles (34%) use masked scalar path.

#define KW 11
#define RAD 5
#define TILE_W 64
#define TILE_H 32
#define IN_H 42                   // TILE_H + 10
#define HQ 66                     // hq stride (pixels; uint2 each) 528B/row
#define H5 68                     // hx5 stride (fp32) 272B/row
#define IMG 512
#define NPLANES 48                // 16*3
#define NBLOCKS (8 * 16 * NPLANES)  // 6144
#define NPIXF (16.0f * 3.0f * 512.0f * 512.0f)

struct GaussW { float g[KW]; };

static __device__ __forceinline__ unsigned pkh2(float a, float b) {
    union { __half2 h; unsigned u; } c;
    c.h = __floats2half2_rn(a, b);
    return c.u;
}
static __device__ __forceinline__ float2 uph2(unsigned u) {
    union { unsigned u; __half2 h; } c;
    c.u = u;
    return __half22float2(c.h);
}

__global__ __launch_bounds__(256, 2) void ssim_fused(
    const float* __restrict__ img1, const float* __restrict__ img2,
    float* __restrict__ accum, unsigned* __restrict__ count,
    float* __restrict__ out, GaussW W)
{
    __shared__ alignas(16) unsigned hq[IN_H][HQ][2];  // {h2(hx,hy), h2(hxx,hyy)}
    __shared__ alignas(16) float    hx5[IN_H][H5];    // gauss-h of x*y, fp32
    // 22176 + 11424 = 33600 B -> 4 blocks/CU

    const int tid = threadIdx.x;
    const int plane = blockIdx.y;
    const int tile  = blockIdx.x;
    const int c0 = (tile & 7) * TILE_W;
    const int r0 = (tile >> 3) * TILE_H;
    const float* __restrict__ p1 = img1 + (size_t)plane * (IMG * IMG);
    const float* __restrict__ p2 = img2 + (size_t)plane * (IMG * IMG);

    // ---- horizontal pass: global (vectorized, register-resident) -> LDS ----
    // thread -> (row = tid>>3 [+32], col group of 8 = (tid&7)*8)
    const int cg = (tid & 7) * 8;
    const int row0 = tid >> 3;
    // 24-col aligned read window [ca, ca+24); taps use cols ca+3 .. ca+20
    const int ca = c0 + cg - 8;   // multiple of 4 (c0 mult 64, cg mult 8)
    const bool colsafe = (ca >= 0) && (ca + 24 <= IMG);

    #pragma unroll
    for (int rr = 0; rr < 2; ++rr) {
        const int row = row0 + rr * 32;
        if (row < IN_H) {
            const int gr = r0 - RAD + row;
            float xa[24], ya[24];
            if ((unsigned)gr < (unsigned)IMG) {
                const float* a = p1 + (ptrdiff_t)gr * IMG + ca;
                const float* b = p2 + (ptrdiff_t)gr * IMG + ca;
                if (colsafe) {
                    #pragma unroll
                    for (int j = 0; j < 6; ++j) {
                        const float4 ta = ((const float4*)a)[j];
                        const float4 tb = ((const float4*)b)[j];
                        xa[4*j+0] = ta.x; xa[4*j+1] = ta.y;
                        xa[4*j+2] = ta.z; xa[4*j+3] = ta.w;
                        ya[4*j+0] = tb.x; ya[4*j+1] = tb.y;
                        ya[4*j+2] = tb.z; ya[4*j+3] = tb.w;
                    }
                } else {
                    #pragma unroll
                    for (int i = 0; i < 24; ++i) {
                        const int gc = ca + i;
                        const bool ok = (unsigned)gc < (unsigned)IMG;
                        xa[i] = ok ? a[i] : 0.f;
                        ya[i] = ok ? b[i] : 0.f;
                    }
                }
            } else {
                #pragma unroll
                for (int i = 0; i < 24; ++i) { xa[i] = 0.f; ya[i] = 0.f; }
            }

            float ax[8] = {}, ay[8] = {}, axx[8] = {}, ayy[8] = {}, axy[8] = {};
            #pragma unroll
            for (int j = 0; j < 18; ++j) {
                const float x = xa[3 + j], y = ya[3 + j];
                const float xx = x * x, yy = y * y, xyv = x * y;
                #pragma unroll
                for (int o = 0; o < 8; ++o) {
                    const int t = j - o;
                    if (t >= 0 && t < KW) {
                        const float w = W.g[t];
                        ax[o]  += w * x;
                        ay[o]  += w * y;
                        axx[o] += w * xx;
                        ayy[o] += w * yy;
                        axy[o] += w * xyv;
                    }
                }
            }

            uint4* dp = (uint4*)&hq[row][cg][0];
            #pragma unroll
            for (int k = 0; k < 4; ++k) {
                uint4 q;
                q.x = pkh2(ax[2*k],    ay[2*k]);
                q.y = pkh2(axx[2*k],   ayy[2*k]);
                q.z = pkh2(ax[2*k+1],  ay[2*k+1]);
                q.w = pkh2(axx[2*k+1], ayy[2*k+1]);
                dp[k] = q;
            }
            float4* d5 = (float4*)&hx5[row][cg];
            d5[0] = make_float4(axy[0], axy[1], axy[2], axy[3]);
            d5[1] = make_float4(axy[4], axy[5], axy[6], axy[7]);
        }
    }
    __syncthreads();   // the ONLY barrier

    // ---- vertical pass + SSIM map ----
    // thread -> (col = tid&63, 8 output rows starting at (tid>>6)*8)
    const int col = tid & 63;
    const int rbase = (tid >> 6) * 8;
    float ox[8] = {}, oy[8] = {}, oxx[8] = {}, oyy[8] = {}, oxy[8] = {};
    #pragma unroll
    for (int m = 0; m < 18; ++m) {
        const int hr = rbase + m;
        const uint2 pw = *(const uint2*)&hq[hr][col][0];  // b64
        const float2 f01 = uph2(pw.x);   // (hx, hy)
        const float2 f23 = uph2(pw.y);   // (hxx, hyy)
        const float v4 = hx5[hr][col];
        #pragma unroll
        for (int o = 0; o < 8; ++o) {
            const int t = m - o;
            if (t >= 0 && t < KW) {
                const float w = W.g[t];
                ox[o]  += w * f01.x;
                oy[o]  += w * f01.y;
                oxx[o] += w * f23.x;
                oyy[o] += w * f23.y;
                oxy[o] += w * v4;
            }
        }
    }

    const float C1 = 1.0e-4f;  // (0.01*L)^2
    const float C2 = 9.0e-4f;  // (0.03*L)^2
    float ssum = 0.f;
    #pragma unroll
    for (int o = 0; o < 8; ++o) {
        const float mu1 = ox[o], mu2 = oy[o];
        const float mu1sq = mu1 * mu1;
        const float mu2sq = mu2 * mu2;
        const float mu12  = mu1 * mu2;
        const float sg1  = oxx[o] - mu1sq;
        const float sg2  = oyy[o] - mu2sq;
        const float sg12 = oxy[o] - mu12;
        const float num = (2.f * mu12 + C1) * (2.f * sg12 + C2);
        const float den = (mu1sq + mu2sq + C1) * (sg1 + sg2 + C2);
        ssum += num / den;
    }

    // ---- reductions: wave shuffle -> LDS (reuse hx5 row 0) -> atomic ----
    #pragma unroll
    for (int off = 32; off > 0; off >>= 1)
        ssum += __shfl_down(ssum, off, 64);
    __syncthreads();                      // all h reads done; safe to reuse
    if ((tid & 63) == 0) hx5[0][tid >> 6] = ssum;
    __syncthreads();
    if (tid == 0) {
        const float bsum = hx5[0][0] + hx5[0][1] + hx5[0][2] + hx5[0][3];
        atomicAdd(accum, bsum);
        __threadfence();
        const unsigned prev = atomicAdd(count, 1u);
        if (prev == (unsigned)(NBLOCKS - 1)) {
            __threadfence();
            const float tot = atomicAdd(accum, 0.0f);  // coherent read
            out[0] = 1.0f - tot / NPIXF;
        }
    }
}

extern "C" void kernel_launch(void* const* d_in, const int* in_sizes, int n_in,
                              void* d_out, int out_size, void* d_ws, size_t ws_size,
                              hipStream_t stream) {
    const float* img1 = (const float*)d_in[0];
    const float* img2 = (const float*)d_in[1];
    float* out = (float*)d_out;
    float* accum = (float*)d_ws;
    unsigned* count = (unsigned*)d_ws + 2;

    hipMemsetAsync(d_ws, 0, 16, stream);  // zero accumulator + counter

    // Gaussian weights on host (double exp, normalized) — matches the
    // reference's float32 window to ~1e-8.
    GaussW W;
    double gd[KW], sum = 0.0;
    for (int i = 0; i < KW; ++i) {
        const double d = (double)(i - KW / 2);
        gd[i] = exp(-(d * d) / (2.0 * 1.5 * 1.5));
        sum += gd[i];
    }
    for (int i = 0; i < KW; ++i) W.g[i] = (float)(gd[i] / sum);

    dim3 grid(8 * 16, NPLANES);
    ssim_fused<<<grid, 256, 0, stream>>>(img1, img2, accum, count, out, W);
}

// Round 11
// 334.847 us; speedup vs baseline: 1.0608x; 1.0608x over previous
//
#include <hip/hip_runtime.h>
#include <math.h>

// SSIM loss, R11 = R1's proven-best structure (all-LDS inner loops, fp32,
// no pack/unpack) + two targeted fixes:
//  1. S_STRIDE 76 -> 77: h-pass read bank = (13r+8g+j)%32 -> exactly 2
//     lanes/bank (free) instead of 8-way conflict (was 8.1M cycles).
//  2. fused atomic finish (validated R5-R10, absmax 0.0) - no 2nd kernel.
// LDS = 2*42*77*4 + 5*42*65*4 = 80,472 B -> 2 blocks/CU.
// Lessons: R2 spill (launch_bounds(256,4)), R5/R7 global-in-inner-loop
// latency, R6 packing adds VALU without cutting stalls.

#define KW 11
#define RAD 5
#define TILE_W 64
#define TILE_H 32
#define IN_W (TILE_W + 2 * RAD)   // 74
#define IN_H (TILE_H + 2 * RAD)   // 42
#define S_STRIDE 77               // ODD: (13r+8g+j)%32 -> 2-way max (free)
#define H_STRIDE 65               // odd: writes 2-way, v-reads stride-1
#define IMG_H 512
#define IMG_W 512
#define NPLANES 48                // 16*3
#define NBLOCKS (8 * 16 * NPLANES)  // 6144
#define NPIXF (16.0f * 3.0f * 512.0f * 512.0f)

struct GaussW { float g[KW]; };

__global__ __launch_bounds__(256, 2) void ssim_fused(
    const float* __restrict__ img1, const float* __restrict__ img2,
    float* __restrict__ accum, unsigned* __restrict__ count,
    float* __restrict__ out, GaussW W)
{
    __shared__ float s1[IN_H][S_STRIDE];
    __shared__ float s2[IN_H][S_STRIDE];
    __shared__ float h[5][IN_H][H_STRIDE];

    const int tid = threadIdx.x;
    const int plane = blockIdx.y;
    const int tile = blockIdx.x;
    const int c0 = (tile & 7) * TILE_W;
    const int r0 = (tile >> 3) * TILE_H;
    const float* __restrict__ p1 = img1 + (size_t)plane * (IMG_H * IMG_W);
    const float* __restrict__ p2 = img2 + (size_t)plane * (IMG_H * IMG_W);

    // ---- stage inputs into LDS with zero padding (conv zero-pad) ----
    for (int idx = tid; idx < IN_H * IN_W; idx += 256) {
        const int row = idx / IN_W;
        const int col = idx - row * IN_W;
        const int gr = r0 - RAD + row;
        const int gc = c0 - RAD + col;
        float v1 = 0.f, v2 = 0.f;
        if ((unsigned)gr < (unsigned)IMG_H && (unsigned)gc < (unsigned)IMG_W) {
            const ptrdiff_t o = (ptrdiff_t)gr * IMG_W + gc;
            v1 = p1[o];
            v2 = p2[o];
        }
        s1[row][col] = v1;
        s2[row][col] = v2;
    }
    __syncthreads();

    // ---- horizontal pass: h[q][row][c] = sum_j g[j] * q(row, c+j-5) ----
    // thread -> (row = tid>>3 [+32], col group of 8 = (tid&7)*8)
    {
        const int cg = (tid & 7) * 8;
        const int row0 = tid >> 3;
        #pragma unroll
        for (int rr = 0; rr < 2; ++rr) {
            const int row = row0 + rr * 32;
            if (row < IN_H) {
                float ax[8]  = {}, ay[8]  = {}, axx[8] = {}, ayy[8] = {}, axy[8] = {};
                #pragma unroll
                for (int j = 0; j < 18; ++j) {
                    const float x = s1[row][cg + j];
                    const float y = s2[row][cg + j];
                    const float xx = x * x, yy = y * y, xy = x * y;
                    #pragma unroll
                    for (int o = 0; o < 8; ++o) {
                        const int t = j - o;
                        if (t >= 0 && t < KW) {
                            const float w = W.g[t];
                            ax[o]  += w * x;
                            ay[o]  += w * y;
                            axx[o] += w * xx;
                            ayy[o] += w * yy;
                            axy[o] += w * xy;
                        }
                    }
                }
                #pragma unroll
                for (int o = 0; o < 8; ++o) {
                    const int col = cg + o;
                    h[0][row][col] = ax[o];
                    h[1][row][col] = ay[o];
                    h[2][row][col] = axx[o];
                    h[3][row][col] = ayy[o];
                    h[4][row][col] = axy[o];
                }
            }
        }
    }
    __syncthreads();

    // ---- vertical pass + SSIM map (stride-1 reads, conflict-free) ----
    // thread -> (col = tid&63, 8 output rows starting at (tid>>6)*8)
    const int col = tid & 63;
    const int rbase = (tid >> 6) * 8;
    float ox[8] = {}, oy[8] = {}, oxx[8] = {}, oyy[8] = {}, oxy[8] = {};
    #pragma unroll
    for (int m = 0; m < 18; ++m) {
        const int hr = rbase + m;
        const float vx  = h[0][hr][col];
        const float vy  = h[1][hr][col];
        const float vxx = h[2][hr][col];
        const float vyy = h[3][hr][col];
        const float vxy = h[4][hr][col];
        #pragma unroll
        for (int o = 0; o < 8; ++o) {
            const int t = m - o;
            if (t >= 0 && t < KW) {
                const float w = W.g[t];
                ox[o]  += w * vx;
                oy[o]  += w * vy;
                oxx[o] += w * vxx;
                oyy[o] += w * vyy;
                oxy[o] += w * vxy;
            }
        }
    }

    const float C1 = 1.0e-4f;  // (0.01*L)^2
    const float C2 = 9.0e-4f;  // (0.03*L)^2
    float ssum = 0.f;
    #pragma unroll
    for (int o = 0; o < 8; ++o) {
        const float mu1 = ox[o], mu2 = oy[o];
        const float mu1sq = mu1 * mu1;
        const float mu2sq = mu2 * mu2;
        const float mu12  = mu1 * mu2;
        const float sg1  = oxx[o] - mu1sq;
        const float sg2  = oyy[o] - mu2sq;
        const float sg12 = oxy[o] - mu12;
        const float num = (2.f * mu12 + C1) * (2.f * sg12 + C2);
        const float den = (mu1sq + mu2sq + C1) * (sg1 + sg2 + C2);
        ssum += num / den;
    }

    // ---- reduction: wave shuffle -> LDS (reuse h[0] row 0) -> atomic ----
    #pragma unroll
    for (int off = 32; off > 0; off >>= 1)
        ssum += __shfl_down(ssum, off, 64);
    __syncthreads();                      // all h reads done; safe to reuse
    if ((tid & 63) == 0) h[0][0][tid >> 6] = ssum;
    __syncthreads();
    if (tid == 0) {
        const float bsum = h[0][0][0] + h[0][0][1] + h[0][0][2] + h[0][0][3];
        atomicAdd(accum, bsum);
        __threadfence();
        const unsigned prev = atomicAdd(count, 1u);
        if (prev == (unsigned)(NBLOCKS - 1)) {
            __threadfence();
            const float tot = atomicAdd(accum, 0.0f);  // coherent read
            out[0] = 1.0f - tot / NPIXF;
        }
    }
}

extern "C" void kernel_launch(void* const* d_in, const int* in_sizes, int n_in,
                              void* d_out, int out_size, void* d_ws, size_t ws_size,
                              hipStream_t stream) {
    const float* img1 = (const float*)d_in[0];
    const float* img2 = (const float*)d_in[1];
    float* out = (float*)d_out;
    float* accum = (float*)d_ws;
    unsigned* count = (unsigned*)d_ws + 2;

    hipMemsetAsync(d_ws, 0, 16, stream);  // zero accumulator + counter

    // Gaussian weights on host (double exp, normalized) — matches the
    // reference's float32 window to ~1e-8.
    GaussW W;
    double gd[KW], sum = 0.0;
    for (int i = 0; i < KW; ++i) {
        const double d = (double)(i - KW / 2);
        gd[i] = exp(-(d * d) / (2.0 * 1.5 * 1.5));
        sum += gd[i];
    }
    for (int i = 0; i < KW; ++i) W.g[i] = (float)(gd[i] / sum);

    dim3 grid(8 * 16, NPLANES);
    ssim_fused<<<grid, 256, 0, stream>>>(img1, img2, accum, count, out, W);
}